// Round 9
// baseline (779.419 us; speedup 1.0000x reference)
//
#include <hip/hip_runtime.h>
#include <hip/hip_bf16.h>

typedef unsigned short u16;
typedef __bf16 bf16x8 __attribute__((ext_vector_type(8)));
typedef unsigned short u16x8 __attribute__((ext_vector_type(8)));
typedef unsigned short u16x4 __attribute__((ext_vector_type(4)));
typedef float f32x4 __attribute__((ext_vector_type(4)));
typedef float f32x16 __attribute__((ext_vector_type(16)));

#define B_ 8
#define T_ 2048
#define E_ 1024
#define H_ 1024
#define M_ (B_ * T_)   // 16384
#define INF __builtin_inff()

__device__ inline u16 f2bf(float f) {
    __bf16 h = (__bf16)f;
    return __builtin_bit_cast(u16, h);
}
__device__ inline float bf2f(u16 u) {
    unsigned v = (unsigned)u << 16;
    return __builtin_bit_cast(float, v);
}
__device__ inline bf16x8 load_frag(const u16* p) {
    u16x8 u = *(const u16x8*)p;
    return __builtin_bit_cast(bf16x8, u);
}
__device__ inline void gload_lds16(const u16* g, u16* l) {
    __builtin_amdgcn_global_load_lds(
        (__attribute__((address_space(1))) unsigned int*)(g),
        (__attribute__((address_space(3))) unsigned int*)(l), 16, 0, 0);
}

// ---------------- cast fp32 -> bf16 ----------------
__global__ void castk(const float* __restrict__ in, u16* __restrict__ out, int n) {
    int i = (blockIdx.x * blockDim.x + threadIdx.x) * 4;
    if (i < n) {
        f32x4 f = *(const f32x4*)(in + i);
        u16x4 u;
        u[0] = f2bf(f[0]); u[1] = f2bf(f[1]); u[2] = f2bf(f[2]); u[3] = f2bf(f[3]);
        *(u16x4*)(out + i) = u;
    }
}

// ---------------- fused QKV GEMM: 256x256 tile, 4-phase/K-tile (R5-verified, ~194us) ----
// BK=32 counted-vmcnt variant (R8) measured ~15us SLOWER -> reverted to this.
__global__ __launch_bounds__(512, 1) void gemm_qkv(const u16* __restrict__ A,
                                                   const u16* __restrict__ W,
                                                   u16* __restrict__ qo,
                                                   u16* __restrict__ ko,
                                                   u16* __restrict__ vo) {
    const int id = blockIdx.x;               // 768 blocks
    const int xcd = id & 7, rr_ = id >> 3;   // XCD-chunked: each XCD owns 8 A-panels
    const int bm = xcd * 8 + (rr_ & 7);      // 0..63
    const int bn = rr_ >> 3;                 // 0..11
    const int tid = threadIdx.x;
    const int w = tid >> 6, lane = tid & 63, quad = lane >> 4, l16 = lane & 15;
    const int wm = w >> 2, wn = w & 3;       // 2M x 4N waves, wave tile 128x64

    __shared__ u16 smem[2 * 32768];          // 128 KB: 2 buf x (A 256x64 | B 256x64)

    f32x4 acc[8][4] = {};                    // 8 m-frags x 4 n-frags of 16x16

    const u16* Ab = A + (size_t)(bm * 256) * E_;
    const u16* Wb = W + (size_t)(bn * 256) * E_;

    auto stage_half = [&](int buf, int mat, int rh, int kt, const u16* gb) {
#pragma unroll
        for (int s = 0; s < 2; s++) {
            int q = s * 512 + tid;
            int row = rh * 128 + (q >> 3), s8 = q & 7;
            int c = s8 ^ (row & 7);
            gload_lds16(gb + (size_t)row * E_ + kt * 64 + c * 8,
                        &smem[buf * 32768 + mat * 16384 + (row * 8 + s8) * 8]);
        }
    };

    // prologue: K-tile 0 into buf 0
    stage_half(0, 0, 0, 0, Ab); stage_half(0, 0, 1, 0, Ab);
    stage_half(0, 1, 0, 0, Wb); stage_half(0, 1, 1, 0, Wb);

    for (int k = 0; k < 16; k++) {
        const int cur = k & 1;
        u16* As = &smem[cur * 32768];
        u16* Bs = &smem[cur * 32768 + 16384];

        // tile start: full drain (loads were issued a full K-tile ago)
        __syncthreads();

#pragma unroll
        for (int p = 0; p < 4; p++) {
            const int mh = p >> 1, ks = p & 1;
            bf16x8 af[4], bfr[4];
#pragma unroll
            for (int ii = 0; ii < 4; ii++) {
                int R = wm * 128 + (mh * 4 + ii) * 16 + l16;
                int c = ks * 4 + quad;
                af[ii] = load_frag(&As[(R * 8 + (c ^ (R & 7))) * 8]);
            }
#pragma unroll
            for (int jj = 0; jj < 4; jj++) {
                int R = wn * 64 + jj * 16 + l16;
                int c = ks * 4 + quad;
                bfr[jj] = load_frag(&Bs[(R * 8 + (c ^ (R & 7))) * 8]);
            }
            if (k < 15 && p < 2) {
                stage_half(cur ^ 1, p, 0, k + 1, p ? Wb : Ab);
                stage_half(cur ^ 1, p, 1, k + 1, p ? Wb : Ab);
            }
            __builtin_amdgcn_sched_barrier(0);
            __builtin_amdgcn_s_barrier();
            asm volatile("s_waitcnt lgkmcnt(0)" ::: "memory");
            __builtin_amdgcn_sched_barrier(0);
            __builtin_amdgcn_s_setprio(1);
#pragma unroll
            for (int ii = 0; ii < 4; ii++)
#pragma unroll
                for (int jj = 0; jj < 4; jj++)
                    acc[mh * 4 + ii][jj] = __builtin_amdgcn_mfma_f32_16x16x32_bf16(
                        af[ii], bfr[jj], acc[mh * 4 + ii][jj], 0, 0, 0);
            __builtin_amdgcn_s_setprio(0);
            __builtin_amdgcn_s_barrier();
        }
    }

    // ---- epilogue: acc -> LDS bf16 (256x256 staged, swizzled) -> coalesced stores ----
    if (bn < 8) {
#pragma unroll
        for (int i = 0; i < 8; i++)
#pragma unroll
            for (int j = 0; j < 4; j++) {
                int n = wn * 64 + j * 16 + l16;
#pragma unroll
                for (int rg = 0; rg < 4; rg++) {
                    int m = wm * 128 + i * 16 + quad * 4 + rg;
                    smem[m * 256 + (((n >> 3) ^ (m & 31)) << 3) + (n & 7)] =
                        f2bf(acc[i][j][rg]);
                }
            }
    } else {
#pragma unroll
        for (int i = 0; i < 8; i++)
#pragma unroll
            for (int j = 0; j < 4; j++) {
                int n = wn * 64 + j * 16 + l16;
                int m0 = wm * 128 + i * 16 + quad * 4;
                u16x4 pk;
#pragma unroll
                for (int rg = 0; rg < 4; rg++) pk[rg] = f2bf(acc[i][j][rg]);
                *(u16x4*)&smem[n * 256 + (((m0 >> 3) ^ (n & 31)) << 3) + (m0 & 7)] = pk;
            }
    }
    __syncthreads();

    const int b = bm >> 3;
    if (bn < 4) {
        // Q row-major
#pragma unroll
        for (int i = 0; i < 16; i++) {
            int c = i * 512 + tid;
            int m = c >> 5, nc = c & 31;
            u16x8 v = *(u16x8*)&smem[m * 256 + ((nc ^ (m & 31)) << 3)];
            *(u16x8*)&qo[(size_t)(bm * 256 + m) * H_ + bn * 256 + nc * 8] = v;
        }
    } else if (bn < 8) {
        // K frag-native
#pragma unroll
        for (int i = 0; i < 16; i++) {
            int c = i * 512 + tid;
            int ln = c & 63, h16c = (c >> 6) & 15, s32c = c >> 10;
            int m = s32c * 32 + (ln & 31);
            int nc = h16c * 2 + (ln >> 5);
            u16x8 v = *(u16x8*)&smem[m * 256 + ((nc ^ (m & 31)) << 3)];
            int s32g = (bm & 7) * 8 + s32c;
            int h16g = (bn - 4) * 16 + h16c;
            *(u16x8*)&ko[(((size_t)b * 64 + s32g) * 64 + h16g) * 512 + ln * 8] = v;
        }
    } else {
        // V frag-native
#pragma unroll
        for (int i = 0; i < 16; i++) {
            int c = i * 512 + tid;
            int ln = c & 63, s16c = (c >> 6) & 15, h32c = c >> 10;
            int n = h32c * 32 + (ln & 31);
            int mc = s16c * 2 + (ln >> 5);
            u16x8 v = *(u16x8*)&smem[n * 256 + ((mc ^ (n & 31)) << 3)];
            int h32g = (bn - 8) * 8 + h32c;
            int s16g = (bm & 7) * 16 + s16c;
            *(u16x8*)&vo[(((size_t)b * 32 + h32g) * 128 + s16g) * 512 + ln * 8] = v;
        }
    }
}

// ---------------- flash attention v8: round-1 structure + loop-carried 16-deep K prefetch ----
// 64 q-rows, 8 waves, LDS 160 KiB, 1 block/CU (LDS-capped -> ~1024 unified regs/wave
// of headroom; current use ~256+64). kbuf[16]: iteration i's first 16 K-frags are
// issued during iteration i-1's PV (land across softmax+barriers); phase 1 consumes
// them while refilling each slot with frags 16..31 -> ~16 loads outstanding, no cold
// start. MFMA order unchanged -> bit-identical numerics.
__global__ __launch_bounds__(512, 2) void attn(const u16* __restrict__ qb,
                                               const u16* __restrict__ kfg,
                                               const u16* __restrict__ vfg,
                                               float* __restrict__ out) {
    const int bid = blockIdx.x;
    const int b = bid & 7;           // batch == XCD
    const int qt = bid >> 3;         // 0..31
    const int t0 = (31 - qt) * 64;
    const int tid = threadIdx.x;
    const int w = tid >> 6, lane = tid & 63;
    const int l5 = lane >> 5, l31 = lane & 31;
    const int srow = tid >> 3, sg = tid & 7;

    __shared__ u16 Qs[64 * 1024];   // 128 KB, [row][chunk ^ (row&7)]
    __shared__ u16 Sp[2 * 64 * 128]; // 32 KB: two bf16 [64][128] partials (chunk-swizzled)
    float* alphas = (float*)(Sp + 8192);  // aliases Sp1[0..255B]; written after Sp1 reads

    const u16* qB = qb + (size_t)b * T_ * H_;
    const u16* kfB = kfg + (size_t)b * 2097152;
    const u16* vfB = vfg + (size_t)b * 2097152;
    const float scale = 0.03125f;   // E^-0.5

    const int ct = w & 3;        // S col-tile (32 cols)
    const int kh = w >> 2;       // k-half

    // loop-carried K prefetch: first 16 frags of iteration s0=0
    bf16x8 kbuf[16];
    {
        const u16* kp0 = kfB + (((size_t)ct) * 64 + kh * 32) * 512 + lane * 8;
#pragma unroll
        for (int i = 0; i < 16; i++) kbuf[i] = load_frag(kp0 + i * 512);
    }

    // stage Q
#pragma unroll
    for (int i = 0; i < 16; i++) {
        int s = i * 512 + tid;
        int row = s >> 7, c = s & 127;
        int cc = c ^ (row & 7);
        gload_lds16(qB + (size_t)(t0 + row) * H_ + cc * 8, &Qs[s * 8]);
    }

    float m_r = -INF, l_r = 0.f;
    f32x16 o[2][4] = {};   // [rowgroup][h-tile]; wave w: H cols [w*128, w*128+128)

    __syncthreads();   // Q staged

    for (int s0 = 0; s0 <= t0 + 63; s0 += 128) {
        // ---- V prefetch group 0 (addresses depend only on s0): issued before
        // phase 1 so the latency is hidden under the whole QK^T phase.
        const u16* vp = vfB + ((size_t)(w * 4) * 128 + (s0 >> 4)) * 512 + lane * 8;
        bf16x8 vbuf[3][4];
#pragma unroll
        for (int ht = 0; ht < 4; ht++)
            vbuf[0][ht] = load_frag(vp + (size_t)ht * 128 * 512);

        // ---- phase 1: partial scores, wave: cols ct*32..+32, k in [kh*512, kh*512+512)
        f32x16 sa0 = {}, sa1 = {};
        {
            const u16* kp = kfB + (((size_t)((s0 >> 5) + ct)) * 64 + kh * 32) * 512 + lane * 8;
            // st 0..15: consume prefetched kbuf, refill slot with frag st+16
#pragma unroll
            for (int st = 0; st < 16; st++) {
                bf16x8 kf = kbuf[st];
                kbuf[st] = load_frag(kp + (st + 16) * 512);
                int cb = (kh * 32 + st) * 2 + l5;
                int x0 = l31 & 7;   // (32+l31)&7 == l31&7
                bf16x8 a0 = load_frag(&Qs[((size_t)l31 * 128 + (cb ^ x0)) * 8]);
                bf16x8 a1 = load_frag(&Qs[((size_t)(32 + l31) * 128 + (cb ^ x0)) * 8]);
                __builtin_amdgcn_s_setprio(1);
                sa0 = __builtin_amdgcn_mfma_f32_32x32x16_bf16(a0, kf, sa0, 0, 0, 0);
                sa1 = __builtin_amdgcn_mfma_f32_32x32x16_bf16(a1, kf, sa1, 0, 0, 0);
                __builtin_amdgcn_s_setprio(0);
            }
            // st 16..31: drain the refilled slots
#pragma unroll
            for (int st = 16; st < 32; st++) {
                bf16x8 kf = kbuf[st - 16];
                int cb = (kh * 32 + st) * 2 + l5;
                int x0 = l31 & 7;
                bf16x8 a0 = load_frag(&Qs[((size_t)l31 * 128 + (cb ^ x0)) * 8]);
                bf16x8 a1 = load_frag(&Qs[((size_t)(32 + l31) * 128 + (cb ^ x0)) * 8]);
                __builtin_amdgcn_s_setprio(1);
                sa0 = __builtin_amdgcn_mfma_f32_32x32x16_bf16(a0, kf, sa0, 0, 0, 0);
                sa1 = __builtin_amdgcn_mfma_f32_32x32x16_bf16(a1, kf, sa1, 0, 0, 0);
                __builtin_amdgcn_s_setprio(0);
            }
        }
        __syncthreads();   // prev PV done reading P(Sp0) + alphas(Sp1)
        {
            u16* Sdst = Sp + kh * 8192;
            int col = ct * 32 + l31;
            int chc = col >> 3, cil = col & 7;
#pragma unroll
            for (int reg = 0; reg < 16; reg++) {
                int row = (reg & 3) + 8 * (reg >> 2) + 4 * l5;
                Sdst[(row * 16 + (chc ^ (row & 7))) * 8 + cil] = f2bf(sa0[reg] * scale);
                int row1 = row + 32;
                Sdst[(row1 * 16 + (chc ^ (row1 & 7))) * 8 + cil] = f2bf(sa1[reg] * scale);
            }
        }
        __syncthreads();   // partials visible

        // ---- phase 2: softmax. thread (srow, sg): cols sg*16..+16
        {
            int sw0 = (sg * 2) ^ (srow & 7), sw1 = (sg * 2 + 1) ^ (srow & 7);
            u16x8 a0 = *(u16x8*)&Sp[(srow * 16 + sw0) * 8];
            u16x8 a1 = *(u16x8*)&Sp[(srow * 16 + sw1) * 8];
            u16x8 b0 = *(u16x8*)&Sp[8192 + (srow * 16 + sw0) * 8];
            u16x8 b1 = *(u16x8*)&Sp[8192 + (srow * 16 + sw1) * 8];
            float v[16];
#pragma unroll
            for (int j = 0; j < 8; j++) v[j] = bf2f(a0[j]) + bf2f(b0[j]);
#pragma unroll
            for (int j = 0; j < 8; j++) v[8 + j] = bf2f(a1[j]) + bf2f(b1[j]);
            int colb = sg * 16;
#pragma unroll
            for (int j = 0; j < 16; j++)
                if (s0 + colb + j > t0 + srow) v[j] = -INF;
            float rmax = v[0];
#pragma unroll
            for (int j = 1; j < 16; j++) rmax = fmaxf(rmax, v[j]);
#pragma unroll
            for (int off = 4; off >= 1; off >>= 1) rmax = fmaxf(rmax, __shfl_xor(rmax, off, 64));
            float mn = fmaxf(m_r, rmax);
            float alpha = __expf(m_r - mn);
            float rsum = 0.f;
            u16x8 p0, p1;
#pragma unroll
            for (int j = 0; j < 8; j++) {
                float p = __expf(v[j] - mn);
                rsum += p; p0[j] = f2bf(p);
            }
#pragma unroll
            for (int j = 0; j < 8; j++) {
                float p = __expf(v[8 + j] - mn);
                rsum += p; p1[j] = f2bf(p);
            }
#pragma unroll
            for (int off = 4; off >= 1; off >>= 1) rsum += __shfl_xor(rsum, off, 64);
            l_r = l_r * alpha + rsum;
            m_r = mn;
            // P in-place over the exact slots this thread read from Sp0
            *(u16x8*)&Sp[(srow * 16 + sw0) * 8] = p0;
            *(u16x8*)&Sp[(srow * 16 + sw1) * 8] = p1;
            __syncthreads();   // all Sp1 reads done
            if (sg == 0) alphas[srow] = alpha;
        }
        __syncthreads();   // P + alphas visible

        // ---- phase 3: PV + next-iteration K prefetch (lands across barriers)
        {
#pragma unroll
            for (int rg = 0; rg < 2; rg++)
#pragma unroll
                for (int reg = 0; reg < 16; reg++) {
                    float al = alphas[rg * 32 + (reg & 3) + 8 * (reg >> 2) + 4 * l5];
#pragma unroll
                    for (int ht = 0; ht < 4; ht++) o[rg][ht][reg] *= al;
                }
            // next-iteration K: 16 frags into kbuf (phase 1 is done with kbuf)
            if (s0 + 128 <= t0 + 63) {
                const u16* kpn = kfB + (((size_t)(((s0 + 128) >> 5) + ct)) * 64 + kh * 32) * 512 + lane * 8;
#pragma unroll
                for (int i = 0; i < 16; i++) kbuf[i] = load_frag(kpn + i * 512);
            }
            int xp = l31 & 7;
#pragma unroll
            for (int ht = 0; ht < 4; ht++)
                vbuf[1][ht] = load_frag(vp + ((size_t)ht * 128 + 1) * 512);
#pragma unroll
            for (int sc = 0; sc < 8; sc++) {
                if (sc < 6) {
#pragma unroll
                    for (int ht = 0; ht < 4; ht++)
                        vbuf[(sc + 2) % 3][ht] = load_frag(vp + ((size_t)ht * 128 + sc + 2) * 512);
                }
                bf16x8 p0 = load_frag(&Sp[((size_t)l31 * 16 + ((sc * 2 + l5) ^ xp)) * 8]);
                bf16x8 p1 = load_frag(&Sp[((size_t)(32 + l31) * 16 + ((sc * 2 + l5) ^ xp)) * 8]);
                __builtin_amdgcn_s_setprio(1);
#pragma unroll
                for (int ht = 0; ht < 4; ht++) {
                    o[0][ht] = __builtin_amdgcn_mfma_f32_32x32x16_bf16(p0, vbuf[sc % 3][ht], o[0][ht], 0, 0, 0);
                    o[1][ht] = __builtin_amdgcn_mfma_f32_32x32x16_bf16(p1, vbuf[sc % 3][ht], o[1][ht], 0, 0, 0);
                }
                __builtin_amdgcn_s_setprio(0);
            }
        }
    }

    // ---- epilogue
    __syncthreads();
    if (sg == 0) alphas[srow] = l_r;
    __syncthreads();
    float* ob = out + (size_t)b * T_ * H_;
#pragma unroll
    for (int rg = 0; rg < 2; rg++)
#pragma unroll
        for (int reg = 0; reg < 16; reg++) {
            int row = rg * 32 + (reg & 3) + 8 * (reg >> 2) + 4 * l5;
            float linv = 1.f / alphas[row];
#pragma unroll
            for (int ht = 0; ht < 4; ht++) {
                int col = w * 128 + ht * 32 + l31;
                ob[(size_t)(t0 + row) * H_ + col] = o[rg][ht][reg] * linv;
            }
        }
}

extern "C" void kernel_launch(void* const* d_in, const int* in_sizes, int n_in,
                              void* d_out, int out_size, void* d_ws, size_t ws_size,
                              hipStream_t stream) {
    const float* x  = (const float*)d_in[0];
    const float* Wk = (const float*)d_in[1];
    const float* Wq = (const float*)d_in[2];
    const float* Wv = (const float*)d_in[3];
    float* out = (float*)d_out;

    char* ws = (char*)d_ws;
    const size_t SZ_XB  = (size_t)M_ * E_ * 2;
    const size_t SZ_W   = (size_t)3 * H_ * E_ * 2;
    const size_t SZ_QKV = (size_t)M_ * H_ * 2;
    u16* xb   = (u16*)(ws);
    u16* wqkv = (u16*)(ws + SZ_XB);
    u16* qb   = (u16*)(ws + SZ_XB + SZ_W);
    u16* kfb  = (u16*)(ws + SZ_XB + SZ_W + SZ_QKV);
    u16* vfb  = (u16*)(ws + SZ_XB + SZ_W + 2 * SZ_QKV);

    castk<<<M_ * E_ / 4 / 256, 256, 0, stream>>>(x, xb, M_ * E_);
    castk<<<H_ * E_ / 4 / 256, 256, 0, stream>>>(Wq, wqkv, H_ * E_);
    castk<<<H_ * E_ / 4 / 256, 256, 0, stream>>>(Wk, wqkv + (size_t)H_ * E_, H_ * E_);
    castk<<<H_ * E_ / 4 / 256, 256, 0, stream>>>(Wv, wqkv + (size_t)2 * H_ * E_, H_ * E_);

    gemm_qkv<<<dim3(768), 512, 0, stream>>>(xb, wqkv, qb, kfb, vfb);

    attn<<<dim3(256), 512, 0, stream>>>(qb, kfb, vfb, out);
}

// Round 10
// 467.506 us; speedup vs baseline: 1.6672x; 1.6672x over previous
//
#include <hip/hip_runtime.h>
#include <hip/hip_bf16.h>

typedef unsigned short u16;
typedef __bf16 bf16x8 __attribute__((ext_vector_type(8)));
typedef unsigned short u16x8 __attribute__((ext_vector_type(8)));
typedef unsigned short u16x4 __attribute__((ext_vector_type(4)));
typedef float f32x4 __attribute__((ext_vector_type(4)));
typedef float f32x16 __attribute__((ext_vector_type(16)));

#define B_ 8
#define T_ 2048
#define E_ 1024
#define H_ 1024
#define M_ (B_ * T_)   // 16384
#define INF __builtin_inff()

__device__ inline u16 f2bf(float f) {
    __bf16 h = (__bf16)f;
    return __builtin_bit_cast(u16, h);
}
__device__ inline float bf2f(u16 u) {
    unsigned v = (unsigned)u << 16;
    return __builtin_bit_cast(float, v);
}
__device__ inline bf16x8 load_frag(const u16* p) {
    u16x8 u = *(const u16x8*)p;
    return __builtin_bit_cast(bf16x8, u);
}
__device__ inline void gload_lds16(const u16* g, u16* l) {
    __builtin_amdgcn_global_load_lds(
        (__attribute__((address_space(1))) unsigned int*)(g),
        (__attribute__((address_space(3))) unsigned int*)(l), 16, 0, 0);
}

// ---------------- cast fp32 -> bf16 ----------------
__global__ void castk(const float* __restrict__ in, u16* __restrict__ out, int n) {
    int i = (blockIdx.x * blockDim.x + threadIdx.x) * 4;
    if (i < n) {
        f32x4 f = *(const f32x4*)(in + i);
        u16x4 u;
        u[0] = f2bf(f[0]); u[1] = f2bf(f[1]); u[2] = f2bf(f[2]); u[3] = f2bf(f[3]);
        *(u16x4*)(out + i) = u;
    }
}

// ---------------- fused QKV GEMM v4: 256x256 tile, BK=32, 3-ring + fine phases + vmcnt(4) ----
// The T3+T4 combo done faithfully under the 160KB LDS budget:
//  - fine per-phase interleave kept from R5 (ds_read || 2 stage-loads || barrier ||
//    lgkmcnt(0) || setprio MFMA || barrier), which R8's coarse lump lost;
//  - counted wait: ring of 3 BK=32 tile-buffers (96 KB); tile k+2 staged during
//    tile k's phases; opening wait vmcnt(4) keeps tile k+1's loads in flight
//    ACROSS all barriers (drain-0 only at the last tile).
// Accumulation k-order identical to R5 -> bit-identical output.
__global__ __launch_bounds__(512, 1) void gemm_qkv(const u16* __restrict__ A,
                                                   const u16* __restrict__ W,
                                                   u16* __restrict__ qo,
                                                   u16* __restrict__ ko,
                                                   u16* __restrict__ vo) {
    const int id = blockIdx.x;               // 768 blocks
    const int xcd = id & 7, rr_ = id >> 3;   // XCD-chunked: each XCD owns 8 A-panels
    const int bm = xcd * 8 + (rr_ & 7);      // 0..63
    const int bn = rr_ >> 3;                 // 0..11
    const int tid = threadIdx.x;
    const int w = tid >> 6, lane = tid & 63, quad = lane >> 4, l16 = lane & 15;
    const int wm = w >> 2, wn = w & 3;       // 2M x 4N waves, wave tile 128x64

    __shared__ u16 smem[65536];              // 128 KB; ring uses first 96 KB

    f32x4 acc[8][4] = {};                    // 8 m-frags x 4 n-frags of 16x16

    const u16* Ab = A + (size_t)(bm * 256) * E_;
    const u16* Wb = W + (size_t)(bn * 256) * E_;

    // stage one matrix (mat 0=A,1=B) of BK=32 tile kt into ring slot r: 2 loads/thread.
    // LDS [row*4+s]*8 linear; source chunk c = s ^ (row&3) (matches read swizzle).
    auto stage_mat = [&](int r, int mat, int kt, const u16* gb) {
#pragma unroll
        for (int s2 = 0; s2 < 2; s2++) {
            int q = s2 * 512 + tid;
            int row = q >> 2, s = q & 3;
            int c = s ^ (row & 3);
            gload_lds16(gb + (size_t)row * E_ + kt * 32 + c * 8,
                        &smem[r * 16384 + mat * 8192 + (row * 4 + s) * 8]);
        }
    };

    // prologue: tiles 0,1 (8 loads in flight)
    stage_mat(0, 0, 0, Ab); stage_mat(0, 1, 0, Wb);
    stage_mat(1, 0, 1, Ab); stage_mat(1, 1, 1, Wb);

    for (int k = 0; k < 32; k++) {
        const int r = k % 3;
        u16* As = &smem[r * 16384];
        u16* Bs = As + 8192;
        const int r2 = (k + 2) % 3;

        // opening: oldest 4 loads (tile k) retired; tile k+1's 4 stay in flight.
        if (k < 31) asm volatile("s_waitcnt vmcnt(4)" ::: "memory");
        else        asm volatile("s_waitcnt vmcnt(0)" ::: "memory");
        __builtin_amdgcn_sched_barrier(0);
        __builtin_amdgcn_s_barrier();        // all waves' tile-k stages visible
        __builtin_amdgcn_sched_barrier(0);

        // ---- phase 0: B frags (shared by both phases) + A rows 0..63 of wave half
        bf16x8 bfr[4], af[4];
#pragma unroll
        for (int jj = 0; jj < 4; jj++) {
            int R = wn * 64 + jj * 16 + l16;
            bfr[jj] = load_frag(&Bs[(R * 4 + (quad ^ (R & 3))) * 8]);
        }
#pragma unroll
        for (int ii = 0; ii < 4; ii++) {
            int R = wm * 128 + ii * 16 + l16;
            af[ii] = load_frag(&As[(R * 4 + (quad ^ (R & 3))) * 8]);
        }
        if (k + 2 < 32) stage_mat(r2, 0, k + 2, Ab);   // tile k+2 A (slot free since k-1)
        __builtin_amdgcn_sched_barrier(0);
        __builtin_amdgcn_s_barrier();
        asm volatile("s_waitcnt lgkmcnt(0)" ::: "memory");
        __builtin_amdgcn_sched_barrier(0);
        __builtin_amdgcn_s_setprio(1);
#pragma unroll
        for (int ii = 0; ii < 4; ii++)
#pragma unroll
            for (int jj = 0; jj < 4; jj++)
                acc[ii][jj] = __builtin_amdgcn_mfma_f32_16x16x32_bf16(
                    af[ii], bfr[jj], acc[ii][jj], 0, 0, 0);
        __builtin_amdgcn_s_setprio(0);
        __builtin_amdgcn_s_barrier();

        // ---- phase 1: A rows 64..127 of wave half
#pragma unroll
        for (int ii = 0; ii < 4; ii++) {
            int R = wm * 128 + 64 + ii * 16 + l16;
            af[ii] = load_frag(&As[(R * 4 + (quad ^ (R & 3))) * 8]);
        }
        if (k + 2 < 32) stage_mat(r2, 1, k + 2, Wb);   // tile k+2 B
        __builtin_amdgcn_sched_barrier(0);
        __builtin_amdgcn_s_barrier();
        asm volatile("s_waitcnt lgkmcnt(0)" ::: "memory");
        __builtin_amdgcn_sched_barrier(0);
        __builtin_amdgcn_s_setprio(1);
#pragma unroll
        for (int ii = 0; ii < 4; ii++)
#pragma unroll
            for (int jj = 0; jj < 4; jj++)
                acc[4 + ii][jj] = __builtin_amdgcn_mfma_f32_16x16x32_bf16(
                    af[ii], bfr[jj], acc[4 + ii][jj], 0, 0, 0);
        __builtin_amdgcn_s_setprio(0);
        __builtin_amdgcn_s_barrier();
    }

    // ---- epilogue (verified): acc -> LDS bf16 (256x256, swizzled) -> coalesced stores ----
    // Safe: final phase barrier passed by all waves; no outstanding gloads (k+2<32 guard).
    if (bn < 8) {
#pragma unroll
        for (int i = 0; i < 8; i++)
#pragma unroll
            for (int j = 0; j < 4; j++) {
                int n = wn * 64 + j * 16 + l16;
#pragma unroll
                for (int rg = 0; rg < 4; rg++) {
                    int m = wm * 128 + i * 16 + quad * 4 + rg;
                    smem[m * 256 + (((n >> 3) ^ (m & 31)) << 3) + (n & 7)] =
                        f2bf(acc[i][j][rg]);
                }
            }
    } else {
#pragma unroll
        for (int i = 0; i < 8; i++)
#pragma unroll
            for (int j = 0; j < 4; j++) {
                int n = wn * 64 + j * 16 + l16;
                int m0 = wm * 128 + i * 16 + quad * 4;
                u16x4 pk;
#pragma unroll
                for (int rg = 0; rg < 4; rg++) pk[rg] = f2bf(acc[i][j][rg]);
                *(u16x4*)&smem[n * 256 + (((m0 >> 3) ^ (n & 31)) << 3) + (m0 & 7)] = pk;
            }
    }
    __syncthreads();

    const int b = bm >> 3;
    if (bn < 4) {
        // Q row-major
#pragma unroll
        for (int i = 0; i < 16; i++) {
            int c = i * 512 + tid;
            int m = c >> 5, nc = c & 31;
            u16x8 v = *(u16x8*)&smem[m * 256 + ((nc ^ (m & 31)) << 3)];
            *(u16x8*)&qo[(size_t)(bm * 256 + m) * H_ + bn * 256 + nc * 8] = v;
        }
    } else if (bn < 8) {
        // K frag-native
#pragma unroll
        for (int i = 0; i < 16; i++) {
            int c = i * 512 + tid;
            int ln = c & 63, h16c = (c >> 6) & 15, s32c = c >> 10;
            int m = s32c * 32 + (ln & 31);
            int nc = h16c * 2 + (ln >> 5);
            u16x8 v = *(u16x8*)&smem[m * 256 + ((nc ^ (m & 31)) << 3)];
            int s32g = (bm & 7) * 8 + s32c;
            int h16g = (bn - 4) * 16 + h16c;
            *(u16x8*)&ko[(((size_t)b * 64 + s32g) * 64 + h16g) * 512 + ln * 8] = v;
        }
    } else {
        // V frag-native
#pragma unroll
        for (int i = 0; i < 16; i++) {
            int c = i * 512 + tid;
            int ln = c & 63, s16c = (c >> 6) & 15, h32c = c >> 10;
            int n = h32c * 32 + (ln & 31);
            int mc = s16c * 2 + (ln >> 5);
            u16x8 v = *(u16x8*)&smem[n * 256 + ((mc ^ (n & 31)) << 3)];
            int h32g = (bn - 8) * 8 + h32c;
            int s16g = (bm & 7) * 16 + s16c;
            *(u16x8*)&vo[(((size_t)b * 32 + h32g) * 128 + s16g) * 512 + ln * 8] = v;
        }
    }
}

// ---------------- flash attention (R1/R5-verified, 236.8 us): 64 q-rows, XCD-pinned ----
// 8 waves, LDS 160 KiB, 1 block/CU. Register budget is at the 256/wave cap
// (128 VGPR + 128 AGPR o-acc) — R9 proved any persistent addition spills.
// Grid 256: batch = bid & 7 pins each batch to one XCD; blocks stream s0 in
// loose lockstep -> shared L2 window (FETCH 51 MB verified).
__global__ __launch_bounds__(512, 2) void attn(const u16* __restrict__ qb,
                                               const u16* __restrict__ kfg,
                                               const u16* __restrict__ vfg,
                                               float* __restrict__ out) {
    const int bid = blockIdx.x;
    const int b = bid & 7;           // batch == XCD
    const int qt = bid >> 3;         // 0..31
    const int t0 = (31 - qt) * 64;
    const int tid = threadIdx.x;
    const int w = tid >> 6, lane = tid & 63;
    const int l5 = lane >> 5, l31 = lane & 31;
    const int srow = tid >> 3, sg = tid & 7;

    __shared__ u16 Qs[64 * 1024];   // 128 KB, [row][chunk ^ (row&7)]
    __shared__ u16 Sp[2 * 64 * 128]; // 32 KB: two bf16 [64][128] partials (chunk-swizzled)
    float* alphas = (float*)(Sp + 8192);  // aliases Sp1[0..255B]; written after Sp1 reads

    const u16* qB = qb + (size_t)b * T_ * H_;
    const u16* kfB = kfg + (size_t)b * 2097152;
    const u16* vfB = vfg + (size_t)b * 2097152;
    const float scale = 0.03125f;   // E^-0.5

    // stage Q
#pragma unroll
    for (int i = 0; i < 16; i++) {
        int s = i * 512 + tid;
        int row = s >> 7, c = s & 127;
        int cc = c ^ (row & 7);
        gload_lds16(qB + (size_t)(t0 + row) * H_ + cc * 8, &Qs[s * 8]);
    }

    float m_r = -INF, l_r = 0.f;
    f32x16 o[2][4] = {};   // [rowgroup][h-tile]; wave w: H cols [w*128, w*128+128)

    const int ct = w & 3;        // S col-tile (32 cols)
    const int kh = w >> 2;       // k-half

    __syncthreads();   // Q staged

    for (int s0 = 0; s0 <= t0 + 63; s0 += 128) {
        // ---- V prefetch group 0 (addresses depend only on s0): issued before
        // phase 1 so the latency is hidden under the whole QK^T phase.
        const u16* vp = vfB + ((size_t)(w * 4) * 128 + (s0 >> 4)) * 512 + lane * 8;
        bf16x8 vbuf[3][4];
#pragma unroll
        for (int ht = 0; ht < 4; ht++)
            vbuf[0][ht] = load_frag(vp + (size_t)ht * 128 * 512);

        // ---- phase 1: partial scores, wave: cols ct*32..+32, k in [kh*512, kh*512+512)
        f32x16 sa0 = {}, sa1 = {};
        {
            const u16* kp = kfB + (((size_t)((s0 >> 5) + ct)) * 64 + kh * 32) * 512 + lane * 8;
#pragma unroll 8
            for (int st = 0; st < 32; st++) {
                bf16x8 kf = load_frag(kp + st * 512);
                int cb = (kh * 32 + st) * 2 + l5;
                int x0 = l31 & 7;   // (32+l31)&7 == l31&7
                bf16x8 a0 = load_frag(&Qs[((size_t)l31 * 128 + (cb ^ x0)) * 8]);
                bf16x8 a1 = load_frag(&Qs[((size_t)(32 + l31) * 128 + (cb ^ x0)) * 8]);
                __builtin_amdgcn_s_setprio(1);
                sa0 = __builtin_amdgcn_mfma_f32_32x32x16_bf16(a0, kf, sa0, 0, 0, 0);
                sa1 = __builtin_amdgcn_mfma_f32_32x32x16_bf16(a1, kf, sa1, 0, 0, 0);
                __builtin_amdgcn_s_setprio(0);
            }
        }
        __syncthreads();   // prev PV done reading P(Sp0) + alphas(Sp1)
        {
            u16* Sdst = Sp + kh * 8192;
            int col = ct * 32 + l31;
            int chc = col >> 3, cil = col & 7;
#pragma unroll
            for (int reg = 0; reg < 16; reg++) {
                int row = (reg & 3) + 8 * (reg >> 2) + 4 * l5;
                Sdst[(row * 16 + (chc ^ (row & 7))) * 8 + cil] = f2bf(sa0[reg] * scale);
                int row1 = row + 32;
                Sdst[(row1 * 16 + (chc ^ (row1 & 7))) * 8 + cil] = f2bf(sa1[reg] * scale);
            }
        }
        __syncthreads();   // partials visible

        // ---- phase 2: softmax. thread (srow, sg): cols sg*16..+16
        {
            int sw0 = (sg * 2) ^ (srow & 7), sw1 = (sg * 2 + 1) ^ (srow & 7);
            u16x8 a0 = *(u16x8*)&Sp[(srow * 16 + sw0) * 8];
            u16x8 a1 = *(u16x8*)&Sp[(srow * 16 + sw1) * 8];
            u16x8 b0 = *(u16x8*)&Sp[8192 + (srow * 16 + sw0) * 8];
            u16x8 b1 = *(u16x8*)&Sp[8192 + (srow * 16 + sw1) * 8];
            float v[16];
#pragma unroll
            for (int j = 0; j < 8; j++) v[j] = bf2f(a0[j]) + bf2f(b0[j]);
#pragma unroll
            for (int j = 0; j < 8; j++) v[8 + j] = bf2f(a1[j]) + bf2f(b1[j]);
            int colb = sg * 16;
#pragma unroll
            for (int j = 0; j < 16; j++)
                if (s0 + colb + j > t0 + srow) v[j] = -INF;
            float rmax = v[0];
#pragma unroll
            for (int j = 1; j < 16; j++) rmax = fmaxf(rmax, v[j]);
#pragma unroll
            for (int off = 4; off >= 1; off >>= 1) rmax = fmaxf(rmax, __shfl_xor(rmax, off, 64));
            float mn = fmaxf(m_r, rmax);
            float alpha = __expf(m_r - mn);
            float rsum = 0.f;
            u16x8 p0, p1;
#pragma unroll
            for (int j = 0; j < 8; j++) {
                float p = __expf(v[j] - mn);
                rsum += p; p0[j] = f2bf(p);
            }
#pragma unroll
            for (int j = 0; j < 8; j++) {
                float p = __expf(v[8 + j] - mn);
                rsum += p; p1[j] = f2bf(p);
            }
#pragma unroll
            for (int off = 4; off >= 1; off >>= 1) rsum += __shfl_xor(rsum, off, 64);
            l_r = l_r * alpha + rsum;
            m_r = mn;
            // P in-place over the exact slots this thread read from Sp0
            *(u16x8*)&Sp[(srow * 16 + sw0) * 8] = p0;
            *(u16x8*)&Sp[(srow * 16 + sw1) * 8] = p1;
            __syncthreads();   // all Sp1 reads done
            if (sg == 0) alphas[srow] = alpha;
        }
        __syncthreads();   // P + alphas visible

        // ---- phase 3: PV. wave w: h cols w*128..+128, all 64 rows
        // V triple-buffered, 2 groups ahead; group 0 arrived during phase 1.
        {
#pragma unroll
            for (int rg = 0; rg < 2; rg++)
#pragma unroll
                for (int reg = 0; reg < 16; reg++) {
                    float al = alphas[rg * 32 + (reg & 3) + 8 * (reg >> 2) + 4 * l5];
#pragma unroll
                    for (int ht = 0; ht < 4; ht++) o[rg][ht][reg] *= al;
                }
            int xp = l31 & 7;
#pragma unroll
            for (int ht = 0; ht < 4; ht++)
                vbuf[1][ht] = load_frag(vp + ((size_t)ht * 128 + 1) * 512);
#pragma unroll
            for (int sc = 0; sc < 8; sc++) {
                if (sc < 6) {
#pragma unroll
                    for (int ht = 0; ht < 4; ht++)
                        vbuf[(sc + 2) % 3][ht] = load_frag(vp + ((size_t)ht * 128 + sc + 2) * 512);
                }
                bf16x8 p0 = load_frag(&Sp[((size_t)l31 * 16 + ((sc * 2 + l5) ^ xp)) * 8]);
                bf16x8 p1 = load_frag(&Sp[((size_t)(32 + l31) * 16 + ((sc * 2 + l5) ^ xp)) * 8]);
                __builtin_amdgcn_s_setprio(1);
#pragma unroll
                for (int ht = 0; ht < 4; ht++) {
                    o[0][ht] = __builtin_amdgcn_mfma_f32_32x32x16_bf16(p0, vbuf[sc % 3][ht], o[0][ht], 0, 0, 0);
                    o[1][ht] = __builtin_amdgcn_mfma_f32_32x32x16_bf16(p1, vbuf[sc % 3][ht], o[1][ht], 0, 0, 0);
                }
                __builtin_amdgcn_s_setprio(0);
            }
        }
    }

    // ---- epilogue
    __syncthreads();
    if (sg == 0) alphas[srow] = l_r;
    __syncthreads();
    float* ob = out + (size_t)b * T_ * H_;
#pragma unroll
    for (int rg = 0; rg < 2; rg++)
#pragma unroll
        for (int reg = 0; reg < 16; reg++) {
            int row = rg * 32 + (reg & 3) + 8 * (reg >> 2) + 4 * l5;
            float linv = 1.f / alphas[row];
#pragma unroll
            for (int ht = 0; ht < 4; ht++) {
                int col = w * 128 + ht * 32 + l31;
                ob[(size_t)(t0 + row) * H_ + col] = o[rg][ht][reg] * linv;
            }
        }
}

extern "C" void kernel_launch(void* const* d_in, const int* in_sizes, int n_in,
                              void* d_out, int out_size, void* d_ws, size_t ws_size,
                              hipStream_t stream) {
    const float* x  = (const float*)d_in[0];
    const float* Wk = (const float*)d_in[1];
    const float* Wq = (const float*)d_in[2];
    const float* Wv = (const float*)d_in[3];
    float* out = (float*)d_out;

    char* ws = (char*)d_ws;
    const size_t SZ_XB  = (size_t)M_ * E_ * 2;
    const size_t SZ_W   = (size_t)3 * H_ * E_ * 2;
    const size_t SZ_QKV = (size_t)M_ * H_ * 2;
    u16* xb   = (u16*)(ws);
    u16* wqkv = (u16*)(ws + SZ_XB);
    u16* qb   = (u16*)(ws + SZ_XB + SZ_W);
    u16* kfb  = (u16*)(ws + SZ_XB + SZ_W + SZ_QKV);
    u16* vfb  = (u16*)(ws + SZ_XB + SZ_W + 2 * SZ_QKV);

    castk<<<M_ * E_ / 4 / 256, 256, 0, stream>>>(x, xb, M_ * E_);
    castk<<<H_ * E_ / 4 / 256, 256, 0, stream>>>(Wq, wqkv, H_ * E_);
    castk<<<H_ * E_ / 4 / 256, 256, 0, stream>>>(Wk, wqkv + (size_t)H_ * E_, H_ * E_);
    castk<<<H_ * E_ / 4 / 256, 256, 0, stream>>>(Wv, wqkv + (size_t)2 * H_ * E_, H_ * E_);

    gemm_qkv<<<dim3(768), 512, 0, stream>>>(xb, wqkv, qb, kfb, vfb);

    attn<<<dim3(256), 512, 0, stream>>>(qb, kfb, vfb, out);
}